// Round 2
// baseline (288.690 us; speedup 1.0000x reference)
//
#include <hip/hip_runtime.h>

#define DIM   1024
#define DST   16
#define NSEQ  8192
#define NB    4

typedef __attribute__((ext_vector_type(8))) short  short8;   // 8 bf16 (4 VGPRs)
typedef __attribute__((ext_vector_type(4))) float  floatx4;  // MFMA acc

__device__ inline unsigned bf16_rne_bits(float f) {
    unsigned u = __float_as_uint(f);
    return (u + 0x7fffu + ((u >> 16) & 1u)) >> 16;
}

// ---------------------------------------------------------------------------
// Kernel 1 (MFMA): T[b][s][n] = sum_c x[b][n][c] * A[c][s]
// Split-bf16 (hi+lo) for ~fp32 accuracy: x@A = xh@Ah + xl@Ah + xh@Al.
// Block = 256 thr (4 waves), 64 rows/block; wave owns 16 rows, K-loop step 32.
// x: global->reg dwordx4, each element read exactly once. A: staged once to
// LDS as bf16 abT[s][k] (stride 1032 -> 2-way bank alias, free). No barriers
// in the K loop.
// ---------------------------------------------------------------------------
#define KP 1032   // padded bf16 row stride (1024 + 8)

__global__ __launch_bounds__(256) void k1_mfma(const float* __restrict__ x,
                                               const float* __restrict__ A,
                                               float* __restrict__ T) {
    __shared__ unsigned short abHi[DST * KP];   // 33,024 B
    __shared__ unsigned short abLo[DST * KP];   // 33,024 B
    const int t  = threadIdx.x;
    const int b  = blockIdx.x >> 7;             // 128 tiles per batch
    const int n0 = (blockIdx.x & 127) * 64;

    // stage A -> bf16 hi/lo, transposed abT[s][k]  (A is [k][s] row-major)
    for (int i = t; i < DIM * DST; i += 256) {
        const int s = i & 15, k = i >> 4;
        const float a = A[i];                   // coalesced: i = k*16+s
        const unsigned hb = bf16_rne_bits(a);
        const float ah = __uint_as_float(hb << 16);
        const unsigned lb = bf16_rne_bits(a - ah);
        abHi[s * KP + k] = (unsigned short)hb;
        abLo[s * KP + k] = (unsigned short)lb;
    }
    __syncthreads();

    const int wave = t >> 6;
    const int lane = t & 63;
    const int m    = lane & 15;      // A-frag row / B-frag col (=s) / C col
    const int q    = lane >> 4;      // k-subblock 0..3

    const int row = n0 + wave * 16 + m;
    const float* xp = x + ((long)(b * NSEQ + row)) * DIM + q * 8;
    const unsigned short* bh = &abHi[m * KP + q * 8];
    const unsigned short* bl = &abLo[m * KP + q * 8];

    floatx4 acc = {0.f, 0.f, 0.f, 0.f};

    // prefetch step 0
    float4 c0 = *(const float4*)(xp);
    float4 c1 = *(const float4*)(xp + 4);

    for (int step = 0; step < 32; ++step) {
        const int ns = (step + 1) & 31;          // last iter: harmless re-read
        const float4 p0 = *(const float4*)(xp + ns * 32);
        const float4 p1 = *(const float4*)(xp + ns * 32 + 4);

        // convert 8 fp32 -> hi/lo bf16 fragments
        short8 ahi, alo;
        const float cf[8] = {c0.x, c0.y, c0.z, c0.w, c1.x, c1.y, c1.z, c1.w};
        #pragma unroll
        for (int j = 0; j < 8; ++j) {
            const unsigned hb = bf16_rne_bits(cf[j]);
            const float fh = __uint_as_float(hb << 16);
            const unsigned lb = bf16_rne_bits(cf[j] - fh);
            ahi[j] = (short)hb;
            alo[j] = (short)lb;
        }
        const short8 bhi = *(const short8*)(bh + step * 32);
        const short8 blo = *(const short8*)(bl + step * 32);

        acc = __builtin_amdgcn_mfma_f32_16x16x32_bf16(ahi, bhi, acc, 0, 0, 0);
        acc = __builtin_amdgcn_mfma_f32_16x16x32_bf16(alo, bhi, acc, 0, 0, 0);
        acc = __builtin_amdgcn_mfma_f32_16x16x32_bf16(ahi, blo, acc, 0, 0, 0);

        c0 = p0; c1 = p1;
    }

    // C/D: col(s) = lane&15, row(n) = q*4 + reg  -> contiguous float4 in T
    float* tp = &T[((long)(b * DST + m)) * NSEQ + n0 + wave * 16 + q * 4];
    *(floatx4*)tp = acc;
}

// ---------------------------------------------------------------------------
// Kernel 2: in-place inclusive cumsum over n for each (b,s) row of T.
// 64 blocks, 256 thr; 32 contiguous elems/thread; wave shuffle-scan; 1 barrier.
// ---------------------------------------------------------------------------
__global__ __launch_bounds__(256) void k2_scan(float* __restrict__ T) {
    __shared__ float wsum[4];
    const int t = threadIdx.x;
    const int b = blockIdx.x >> 4;
    const int s = blockIdx.x & 15;
    float* row = T + ((long)(b * DST + s)) * NSEQ;
    const int base = t * 32;

    float v[32];
    #pragma unroll
    for (int j = 0; j < 8; ++j) {
        const float4 f = *(const float4*)&row[base + 4 * j];
        v[4 * j + 0] = f.x; v[4 * j + 1] = f.y;
        v[4 * j + 2] = f.z; v[4 * j + 3] = f.w;
    }
    float run = 0.f;
    #pragma unroll
    for (int i = 0; i < 32; ++i) { run += v[i]; v[i] = run; }

    // inclusive scan of per-thread totals within the wave (no barriers)
    const int lane = t & 63;
    float sc = run;
    #pragma unroll
    for (int off = 1; off < 64; off <<= 1) {
        const float u = __shfl_up(sc, off, 64);
        if (lane >= off) sc += u;
    }
    const int w = t >> 6;
    if (lane == 63) wsum[w] = sc;
    __syncthreads();

    float woff = 0.f;
    #pragma unroll
    for (int i = 0; i < 4; ++i) woff += (i < w) ? wsum[i] : 0.f;
    const float excl = woff + sc - run;   // exclusive offset for this thread

    #pragma unroll
    for (int j = 0; j < 8; ++j) {
        const float4 f = make_float4(v[4 * j + 0] + excl, v[4 * j + 1] + excl,
                                     v[4 * j + 2] + excl, v[4 * j + 3] + excl);
        *(float4*)&row[base + 4 * j] = f;
    }
}

// ---------------------------------------------------------------------------
// Kernel 3: out[b][n][c] = sum_s T[b][s][n] * D[s][c]
// Block = 256 thr, 64 rows/block; thread owns c-quad 4t..4t+3; D in 64 VGPRs;
// state tile staged transposed in LDS (broadcast reads). Write-wall bound.
// ---------------------------------------------------------------------------
#define K3_W 64

__global__ __launch_bounds__(256) void k3_out(const float* __restrict__ T,
                                              const float* __restrict__ D,
                                              float* __restrict__ out) {
    __shared__ float sp[K3_W * 20];   // [n][s] padded 16->20
    const int t  = threadIdx.x;
    const int b  = blockIdx.x >> 7;
    const int n0 = (blockIdx.x & 127) * K3_W;

    #pragma unroll
    for (int j = 0; j < 4; ++j) {
        const int idx = j * 256 + t;
        const int ss  = idx >> 6;     // 0..15
        const int nn  = idx & 63;
        sp[nn * 20 + ss] = T[((long)(b * DST + ss)) * NSEQ + n0 + nn];
    }

    float4 dreg[16];
    #pragma unroll
    for (int ss = 0; ss < 16; ++ss)
        dreg[ss] = *(const float4*)&D[ss * DIM + 4 * t];

    __syncthreads();

    float* ob = out + ((long)(b * NSEQ + n0)) * DIM + 4 * t;
    for (int r = 0; r < K3_W; ++r) {
        const float4 s0 = *(const float4*)&sp[r * 20 + 0];
        const float4 s1 = *(const float4*)&sp[r * 20 + 4];
        const float4 s2 = *(const float4*)&sp[r * 20 + 8];
        const float4 s3 = *(const float4*)&sp[r * 20 + 12];
        const float sv[16] = {s0.x, s0.y, s0.z, s0.w, s1.x, s1.y, s1.z, s1.w,
                              s2.x, s2.y, s2.z, s2.w, s3.x, s3.y, s3.z, s3.w};
        float4 o = make_float4(0.f, 0.f, 0.f, 0.f);
        #pragma unroll
        for (int ss = 0; ss < 16; ++ss) {
            o.x += sv[ss] * dreg[ss].x;
            o.y += sv[ss] * dreg[ss].y;
            o.z += sv[ss] * dreg[ss].z;
            o.w += sv[ss] * dreg[ss].w;
        }
        *(float4*)(ob + (long)r * DIM) = o;
    }
}

// ---------------------------------------------------------------------------
extern "C" void kernel_launch(void* const* d_in, const int* in_sizes, int n_in,
                              void* d_out, int out_size, void* d_ws, size_t ws_size,
                              hipStream_t stream) {
    const float* x = (const float*)d_in[0];   // [4, 8192, 1024]
    const float* A = (const float*)d_in[1];   // [1024, 16]
    const float* D = (const float*)d_in[2];   // [16, 1024]
    float* out = (float*)d_out;               // [4, 8192, 1024]
    float* T   = (float*)d_ws;                // [4, 16, 8192] = 2 MiB scratch

    k1_mfma<<<dim3(NB * 128), dim3(256), 0, stream>>>(x, A, T);
    k2_scan<<<dim3(NB * DST), dim3(256), 0, stream>>>(T);
    k3_out <<<dim3(NB * 128), dim3(256), 0, stream>>>(T, D, out);
}

// Round 3
// 278.696 us; speedup vs baseline: 1.0359x; 1.0359x over previous
//
#include <hip/hip_runtime.h>

#define DIM   1024
#define DST   16
#define NSEQ  8192
#define NB    4
#define NCH   128    // 64-row chunks per batch row-space (8192/64)

typedef __attribute__((ext_vector_type(8))) short  short8;   // 8 bf16 (4 VGPRs)
typedef __attribute__((ext_vector_type(4))) float  floatx4;  // MFMA acc

__device__ inline unsigned bf16_rne_bits(float f) {
    unsigned u = __float_as_uint(f);
    return (u + 0x7fffu + ((u >> 16) & 1u)) >> 16;
}

// ---------------------------------------------------------------------------
// Kernel A: per 64-row chunk: P = x@A (split-bf16 MFMA, ~fp32 accuracy),
// then in-chunk inclusive cumsum over the 64 rows (regs + shuffles + LDS),
// write locally-scanned tile Tl[b][chunk][s][64] + chunk totals ct[b][s][128].
// 512 blocks x 256 thr. No barriers in K loop; prefetch depth 4.
// ---------------------------------------------------------------------------
#define KP 1032   // padded bf16 row stride (1024 + 8): 2-way bank alias = free

__global__ __launch_bounds__(256, 2) void kA(const float* __restrict__ x,
                                             const float* __restrict__ A,
                                             float* __restrict__ Tl,
                                             float* __restrict__ ct) {
    __shared__ unsigned short abHi[DST * KP];   // 33,024 B
    __shared__ unsigned short abLo[DST * KP];   // 33,024 B
    __shared__ float wtot[4][16];
    const int t     = threadIdx.x;
    const int b     = blockIdx.x >> 7;
    const int chunk = blockIdx.x & 127;
    const int n0    = chunk * 64;

    // stage A -> bf16 hi/lo, transposed abT[s][k]; A row-major [k][16]
    #pragma unroll
    for (int j = 0; j < 16; ++j) {
        const int f  = (j * 256 + t) * 4;       // flat, s0 = f&15 in {0,4,8,12}
        const int k  = f >> 4;
        const int s0 = f & 15;
        const float4 a4 = *(const float4*)&A[f];
        const float av[4] = {a4.x, a4.y, a4.z, a4.w};
        #pragma unroll
        for (int i = 0; i < 4; ++i) {
            const unsigned hb = bf16_rne_bits(av[i]);
            const float ah = __uint_as_float(hb << 16);
            const unsigned lb = bf16_rne_bits(av[i] - ah);
            abHi[(s0 + i) * KP + k] = (unsigned short)hb;
            abLo[(s0 + i) * KP + k] = (unsigned short)lb;
        }
    }
    __syncthreads();

    const int wave = t >> 6;
    const int lane = t & 63;
    const int m    = lane & 15;      // A-frag row (x row) / B-frag col (s) / C col (s)
    const int q    = lane >> 4;      // k-subblock 0..3; C rows q*4..q*4+3

    const float* xp = x + ((long)(b * NSEQ + n0 + wave * 16 + m)) * DIM + q * 8;
    const unsigned short* bh = &abHi[m * KP + q * 8];
    const unsigned short* bl = &abLo[m * KP + q * 8];

    floatx4 acc = {0.f, 0.f, 0.f, 0.f};

    float4 pf[4][2];
    #pragma unroll
    for (int i = 0; i < 4; ++i) {
        pf[i][0] = *(const float4*)(xp + i * 32);
        pf[i][1] = *(const float4*)(xp + i * 32 + 4);
    }

    #pragma unroll 4
    for (int step = 0; step < 32; ++step) {
        const int slot = step & 3;
        const float4 c0 = pf[slot][0];
        const float4 c1 = pf[slot][1];
        const int ns = (step + 4) & 31;          // wraps at end: harmless L1 re-read
        pf[slot][0] = *(const float4*)(xp + ns * 32);
        pf[slot][1] = *(const float4*)(xp + ns * 32 + 4);

        short8 ahi, alo;
        const float cf[8] = {c0.x, c0.y, c0.z, c0.w, c1.x, c1.y, c1.z, c1.w};
        #pragma unroll
        for (int j = 0; j < 8; ++j) {
            const unsigned hb = bf16_rne_bits(cf[j]);
            const float fh = __uint_as_float(hb << 16);
            const unsigned lb = bf16_rne_bits(cf[j] - fh);
            ahi[j] = (short)hb;
            alo[j] = (short)lb;
        }
        const short8 bhi = *(const short8*)(bh + step * 32);
        const short8 blo = *(const short8*)(bl + step * 32);

        acc = __builtin_amdgcn_mfma_f32_16x16x32_bf16(ahi, bhi, acc, 0, 0, 0);
        acc = __builtin_amdgcn_mfma_f32_16x16x32_bf16(alo, bhi, acc, 0, 0, 0);
        acc = __builtin_amdgcn_mfma_f32_16x16x32_bf16(ahi, blo, acc, 0, 0, 0);
    }

    // ---- in-chunk cumsum over 64 rows, per s ----
    // lane holds rows (wave*16 + q*4 + i) for s = m.
    acc[1] += acc[0]; acc[2] += acc[1]; acc[3] += acc[2];   // serial-4 inclusive
    const float g = acc[3];                                  // own quad total
    float v = g;                                             // scan quad totals over q
    {
        const float u1 = __shfl_up(v, 16, 64); if (lane >= 16) v += u1;
        const float u2 = __shfl_up(v, 32, 64); if (lane >= 32) v += u2;
    }
    const float exclq = v - g;                               // quads < q
    if (lane >= 48) wtot[wave][m] = v;                       // wave total per s
    __syncthreads();

    float woff = 0.f;
    #pragma unroll
    for (int w = 0; w < 4; ++w) woff += (w < wave) ? wtot[w][m] : 0.f;
    const float add = exclq + woff;
    acc[0] += add; acc[1] += add; acc[2] += add; acc[3] += add;

    // chunk totals
    if (t < 16) {
        const float tot = wtot[0][t] + wtot[1][t] + wtot[2][t] + wtot[3][t];
        ct[((long)(b * DST + t)) * NCH + chunk] = tot;
    }

    // Tl[b][chunk][s][nn]: lane writes nn = wave*16 + q*4 .. +3 for s = m
    float* tp = &Tl[(((long)(b * NCH + chunk)) * DST + m) * 64 + wave * 16 + q * 4];
    *(floatx4*)tp = acc;
}

// ---------------------------------------------------------------------------
// Kernel B: out[b][n][c] = sum_s (Tl_local_cumsum + chunk_prefix)[s][n] * D[s][c]
// 512 blocks x 256 thr; thread owns c-quad 4t..4t+3; D in 64 VGPRs;
// tile staged transposed in LDS with chunk prefix folded in. Write-wall bound.
// ---------------------------------------------------------------------------
__global__ __launch_bounds__(256) void kB(const float* __restrict__ Tl,
                                          const float* __restrict__ ct,
                                          const float* __restrict__ D,
                                          float* __restrict__ out) {
    __shared__ float sp[64 * 20];   // [nn][s] padded 16->20 (keeps 16B align)
    __shared__ float pe[16];
    const int t     = threadIdx.x;
    const int b     = blockIdx.x >> 7;
    const int chunk = blockIdx.x & 127;
    const int n0    = chunk * 64;

    // exclusive chunk prefix per s (L2-hot, <=127 independent loads)
    if (t < 16) {
        const float* p = &ct[((long)(b * DST + t)) * NCH];
        float s = 0.f;
        for (int c = 0; c < chunk; ++c) s += p[c];
        pe[t] = s;
    }

    float4 dreg[16];
    #pragma unroll
    for (int ss = 0; ss < 16; ++ss)
        dreg[ss] = *(const float4*)&D[ss * DIM + 4 * t];

    __syncthreads();

    // stage tile (+prefix) transposed: thread covers flat [s][nn] idx 4t..4t+3
    {
        const int s4 = (4 * t) >> 6;
        const int nn = (4 * t) & 63;
        const float4 v = *(const float4*)&Tl[(((long)(b * NCH + chunk)) * DST + s4) * 64 + nn];
        const float p = pe[s4];
        sp[(nn + 0) * 20 + s4] = v.x + p;
        sp[(nn + 1) * 20 + s4] = v.y + p;
        sp[(nn + 2) * 20 + s4] = v.z + p;
        sp[(nn + 3) * 20 + s4] = v.w + p;
    }
    __syncthreads();

    float* ob = out + ((long)(b * NSEQ + n0)) * DIM + 4 * t;
    for (int r = 0; r < 64; ++r) {
        const float4 s0 = *(const float4*)&sp[r * 20 + 0];
        const float4 s1 = *(const float4*)&sp[r * 20 + 4];
        const float4 s2 = *(const float4*)&sp[r * 20 + 8];
        const float4 s3 = *(const float4*)&sp[r * 20 + 12];
        const float sv[16] = {s0.x, s0.y, s0.z, s0.w, s1.x, s1.y, s1.z, s1.w,
                              s2.x, s2.y, s2.z, s2.w, s3.x, s3.y, s3.z, s3.w};
        float4 o = make_float4(0.f, 0.f, 0.f, 0.f);
        #pragma unroll
        for (int ss = 0; ss < 16; ++ss) {
            o.x += sv[ss] * dreg[ss].x;
            o.y += sv[ss] * dreg[ss].y;
            o.z += sv[ss] * dreg[ss].z;
            o.w += sv[ss] * dreg[ss].w;
        }
        *(float4*)(ob + (long)r * DIM) = o;
    }
}

// ---------------------------------------------------------------------------
extern "C" void kernel_launch(void* const* d_in, const int* in_sizes, int n_in,
                              void* d_out, int out_size, void* d_ws, size_t ws_size,
                              hipStream_t stream) {
    const float* x = (const float*)d_in[0];   // [4, 8192, 1024]
    const float* A = (const float*)d_in[1];   // [1024, 16]
    const float* D = (const float*)d_in[2];   // [16, 1024]
    float* out = (float*)d_out;               // [4, 8192, 1024]
    float* Tl  = (float*)d_ws;                // [4][128][16][64] = 2 MiB
    float* ct  = Tl + (long)NB * NCH * DST * 64;   // [4][16][128] = 32 KiB

    kA<<<dim3(NB * NCH), dim3(256), 0, stream>>>(x, A, Tl, ct);
    kB<<<dim3(NB * NCH), dim3(256), 0, stream>>>(Tl, ct, D, out);
}